// Round 1
// baseline (1435.803 us; speedup 1.0000x reference)
//
#include <hip/hip_runtime.h>

// GIN forward, MI355X. Pipeline:
//  CSR build (hist/scan/scatter)  -> pull-aggregation without atomics
//  BN handled as lazy affine: s=rsqrt(v+eps)*g, t=be-m*s, applied fused+relu in consumers
//  GEMMs: 1 thread/row, acc[64], W via wave-uniform (scalar) loads

#define HID 64
#define LAYERS 3
#define BN_EPS 1e-5f

__device__ __forceinline__ float relu_aff(float x, float s, float t) {
    return fmaxf(fmaf(x, s, t), 0.f);
}

// ---------------- CSR build ----------------
__global__ void k_hist(const int* __restrict__ dst, int* __restrict__ cnt, int E) {
    int e = blockIdx.x * 256 + threadIdx.x;
    if (e < E) atomicAdd(&cnt[dst[e]], 1);
}

__global__ void k_scan1(const int* __restrict__ cnt, int* __restrict__ part, int n) {
    __shared__ int sm[256];
    int i = blockIdx.x * 256 + threadIdx.x;
    sm[threadIdx.x] = (i < n) ? cnt[i] : 0;
    __syncthreads();
    for (int s = 128; s > 0; s >>= 1) {
        if (threadIdx.x < s) sm[threadIdx.x] += sm[threadIdx.x + s];
        __syncthreads();
    }
    if (threadIdx.x == 0) part[blockIdx.x] = sm[0];
}

// 1 block, 512 threads: exclusive scan of part[0..nb), nb<=512; writes total to row_off[N]
__global__ void k_scan2(int* part, int nb, int* row_off, int N) {
    int lane = threadIdx.x & 63, wid = threadIdx.x >> 6;
    int v = (threadIdx.x < nb) ? part[threadIdx.x] : 0;
    int incl = v;
    for (int d = 1; d < 64; d <<= 1) { int y = __shfl_up(incl, d); if (lane >= d) incl += y; }
    __shared__ int ws[8];
    if (lane == 63) ws[wid] = incl;
    __syncthreads();
    if (threadIdx.x == 0) { int a = 0; for (int w = 0; w < 8; w++) { int t = ws[w]; ws[w] = a; a += t; } }
    __syncthreads();
    int excl = incl - v + ws[wid];
    if (threadIdx.x < nb) part[threadIdx.x] = excl;
    if (threadIdx.x == nb - 1) row_off[N] = excl + v;
}

// per-chunk exclusive scan + add block offset; cnt may alias row_off (read-before-write separated by barrier)
__global__ void k_scan3(const int* cnt, const int* __restrict__ part,
                        int* row_off, int* cursor, int n) {
    int i = blockIdx.x * 256 + threadIdx.x;
    int lane = threadIdx.x & 63, wid = threadIdx.x >> 6;
    int v = (i < n) ? cnt[i] : 0;
    int incl = v;
    for (int d = 1; d < 64; d <<= 1) { int y = __shfl_up(incl, d); if (lane >= d) incl += y; }
    __shared__ int ws[4];
    if (lane == 63) ws[wid] = incl;
    __syncthreads();
    if (threadIdx.x == 0) { int a = 0; for (int w = 0; w < 4; w++) { int t = ws[w]; ws[w] = a; a += t; } }
    __syncthreads();
    int excl = incl - v + ws[wid] + part[blockIdx.x];
    if (i < n) { row_off[i] = excl; cursor[i] = excl; }
}

__global__ void k_scatter(const int* __restrict__ src, const int* __restrict__ dst,
                          int* __restrict__ cursor, int* __restrict__ col, int E) {
    int e = blockIdx.x * 256 + threadIdx.x;
    if (e < E) {
        int d = dst[e];
        int p = atomicAdd(&cursor[d], 1);
        col[p] = src[e];
    }
}

// ---------------- aggregation: o = (1+eps)*h + sum_{src->node} h[src] ----------------
// h[x][f] = relu(hb[x*64+f]*s[f]+t[f]) computed on the fly. 1 wave per node, lane = feature.
__global__ __launch_bounds__(256) void k_agg(const float* __restrict__ hb, const float* __restrict__ st,
                                             const int* __restrict__ row_off, const int* __restrict__ col,
                                             const float* __restrict__ epsp, int li,
                                             float* __restrict__ o, int n) {
    int wid = threadIdx.x >> 6, lane = threadIdx.x & 63;
    int node = blockIdx.x * 4 + wid;
    if (node >= n) return;
    float s = st[lane], t = st[HID + lane];
    float ope = 1.f + epsp[li];
    float acc = ope * relu_aff(hb[(size_t)node * HID + lane], s, t);
    int b0 = row_off[node], b1 = row_off[node + 1];
    for (int e = b0; e < b1; e++) {
        int sn = col[e];
        acc += relu_aff(hb[(size_t)sn * HID + lane], s, t);
    }
    o[(size_t)node * HID + lane] = acc;
}

// ---------------- GEMM: C[n x NCOL] = act(A[n x 64]) @ W[64 x NCOL] + bias ----------------
template <int NCOL, bool AFF>
__global__ __launch_bounds__(256) void k_gemm64(const float* __restrict__ A, const float* __restrict__ st,
                                                const float* __restrict__ W, const float* __restrict__ bias,
                                                float* __restrict__ C, int n) {
    int row = blockIdx.x * 256 + threadIdx.x;
    if (row >= n) return;
    float acc[NCOL];
#pragma unroll
    for (int j = 0; j < NCOL; j++) acc[j] = bias[j];
    const float4* a4 = (const float4*)(A + (size_t)row * HID);
    for (int kk = 0; kk < HID / 4; kk++) {
        float4 av = a4[kk];
        float a[4] = {av.x, av.y, av.z, av.w};
#pragma unroll
        for (int u = 0; u < 4; u++) {
            int k = kk * 4 + u;
            float xv = a[u];
            if (AFF) xv = relu_aff(xv, st[k], st[HID + k]);
#pragma unroll
            for (int j = 0; j < NCOL; j++) acc[j] = fmaf(xv, W[k * NCOL + j], acc[j]);
        }
    }
    float* c = C + (size_t)row * NCOL;
    if constexpr (NCOL % 4 == 0) {
#pragma unroll
        for (int j = 0; j < NCOL / 4; j++)
            ((float4*)c)[j] = make_float4(acc[4 * j], acc[4 * j + 1], acc[4 * j + 2], acc[4 * j + 3]);
    } else {
#pragma unroll
        for (int j = 0; j < NCOL; j++) c[j] = acc[j];
    }
}

// concat GEMM: C = [h0|h1|h2|h3] @ W[256 x 64] + bias, h_p = relu(buf_p*s_p+t_p)
__global__ __launch_bounds__(256) void k_gemm_out1(const float* __restrict__ B0, const float* __restrict__ B1,
                                                   const float* __restrict__ B2, const float* __restrict__ B3,
                                                   const float* __restrict__ S0, const float* __restrict__ S1,
                                                   const float* __restrict__ S2, const float* __restrict__ S3,
                                                   const float* __restrict__ W, const float* __restrict__ bias,
                                                   float* __restrict__ C, int n) {
    int row = blockIdx.x * 256 + threadIdx.x;
    if (row >= n) return;
    float acc[HID];
#pragma unroll
    for (int j = 0; j < HID; j++) acc[j] = bias[j];
    const float* bufs[4] = {B0, B1, B2, B3};
    const float* sts[4] = {S0, S1, S2, S3};
#pragma unroll
    for (int pp = 0; pp < 4; pp++) {
        const float4* a4 = (const float4*)(bufs[pp] + (size_t)row * HID);
        const float* stp = sts[pp];
        const float* Wp = W + pp * HID * HID;
        for (int kk = 0; kk < HID / 4; kk++) {
            float4 av = a4[kk];
            float a[4] = {av.x, av.y, av.z, av.w};
#pragma unroll
            for (int u = 0; u < 4; u++) {
                int k = kk * 4 + u;
                float xv = relu_aff(a[u], stp[k], stp[HID + k]);
#pragma unroll
                for (int j = 0; j < HID; j++) acc[j] = fmaf(xv, Wp[k * HID + j], acc[j]);
            }
        }
    }
    float4* c4 = (float4*)(C + (size_t)row * HID);
#pragma unroll
    for (int j = 0; j < HID / 4; j++)
        c4[j] = make_float4(acc[4 * j], acc[4 * j + 1], acc[4 * j + 2], acc[4 * j + 3]);
}

// ---------------- column stats (sum, sumsq) ----------------
__global__ __launch_bounds__(256) void k_colstats(const float* __restrict__ X, float* __restrict__ raw,
                                                  long long n64) {
    long long stride = (long long)gridDim.x * 256;
    long long i0 = (long long)blockIdx.x * 256 + threadIdx.x;
    int col = threadIdx.x & 63;
    float s = 0.f, q = 0.f;
    for (long long i = i0; i < n64; i += stride) { float v = X[i]; s += v; q = fmaf(v, v, q); }
    __shared__ float ls[256], lq[256];
    ls[threadIdx.x] = s; lq[threadIdx.x] = q;
    __syncthreads();
    if (threadIdx.x < 64) {
        s = ls[threadIdx.x] + ls[threadIdx.x + 64] + ls[threadIdx.x + 128] + ls[threadIdx.x + 192];
        q = lq[threadIdx.x] + lq[threadIdx.x + 64] + lq[threadIdx.x + 128] + lq[threadIdx.x + 192];
        atomicAdd(&raw[col], s);
        atomicAdd(&raw[64 + col], q);
    }
}

// in-place z = relu(x*s+t) + stats(z)
__global__ __launch_bounds__(256) void k_affine_stats(float* __restrict__ X, const float* __restrict__ st,
                                                      float* __restrict__ raw, long long n64) {
    long long stride = (long long)gridDim.x * 256;
    long long i0 = (long long)blockIdx.x * 256 + threadIdx.x;
    int col = threadIdx.x & 63;
    float sA = st[col], tA = st[64 + col];
    float s = 0.f, q = 0.f;
    for (long long i = i0; i < n64; i += stride) {
        float v = relu_aff(X[i], sA, tA);
        X[i] = v;
        s += v; q = fmaf(v, v, q);
    }
    __shared__ float ls[256], lq[256];
    ls[threadIdx.x] = s; lq[threadIdx.x] = q;
    __syncthreads();
    if (threadIdx.x < 64) {
        s = ls[threadIdx.x] + ls[threadIdx.x + 64] + ls[threadIdx.x + 128] + ls[threadIdx.x + 192];
        q = lq[threadIdx.x] + lq[threadIdx.x + 64] + lq[threadIdx.x + 128] + lq[threadIdx.x + 192];
        atomicAdd(&raw[col], s);
        atomicAdd(&raw[64 + col], q);
    }
}

// sums -> affine (s,t). 64 threads.
__global__ void k_fin(const float* __restrict__ raw, const float* __restrict__ g, const float* __restrict__ b,
                      float* __restrict__ st, float invN) {
    int j = threadIdx.x;
    float m = raw[j] * invN;
    float v = fmaf(-m, m, raw[64 + j] * invN);
    float r = rsqrtf(v + BN_EPS);
    float s = r * g[j];
    st[j] = s;
    st[64 + j] = fmaf(-m, s, b[j]);
}

extern "C" void kernel_launch(void* const* d_in, const int* in_sizes, int n_in,
                              void* d_out, int out_size, void* d_ws, size_t ws_size,
                              hipStream_t stream) {
    const float* x = (const float*)d_in[0];
    const int* ei = (const int*)d_in[1];
    const float* W_in = (const float*)d_in[2];
    const float* b_in = (const float*)d_in[3];
    const float* g_in = (const float*)d_in[4];
    const float* be_in = (const float*)d_in[5];
    const float* epsp = (const float*)d_in[6];
    const float* W1 = (const float*)d_in[7];
    const float* b1 = (const float*)d_in[8];
    const float* g1 = (const float*)d_in[9];
    const float* be1 = (const float*)d_in[10];
    const float* W2 = (const float*)d_in[11];
    const float* b2 = (const float*)d_in[12];
    const float* g2 = (const float*)d_in[13];
    const float* be2 = (const float*)d_in[14];
    const float* g_post = (const float*)d_in[15];
    const float* be_post = (const float*)d_in[16];
    const float* W_out1 = (const float*)d_in[17];
    const float* b_out1 = (const float*)d_in[18];
    const float* g_out = (const float*)d_in[19];
    const float* be_out = (const float*)d_in[20];
    const float* W_out2 = (const float*)d_in[21];
    const float* b_out2 = (const float*)d_in[22];

    const int N = in_sizes[0] / HID;
    const int E = in_sizes[1] / 2;
    const int* srcp = ei;
    const int* dstp = ei + E;

    size_t NODE = (size_t)N * HID;
    float* f = (float*)d_ws;
    float* pre0 = f;                 // stage-0 pre-BN (kept for concat)
    float* z0 = f + NODE;            // layer pre2 -> (in place) post-BN2-relu, kept for concat
    float* z1 = f + 2 * NODE;
    float* z2 = f + 3 * NODE;
    float* o = f + 4 * NODE;         // aggregation output
    float* p = f + 5 * NODE;         // gemm1 output / head pre-BN (reused)
    int* rc = (int*)(f + 6 * NODE);  // counts -> row offsets, N+1
    int* cursor = rc + (N + 1);
    int* col = cursor + N;           // E
    int* part = col + E;             // scan partials, <=512
    float* raw = (float*)(part + 512);  // 11 stages x {sum[64], sumsq[64]}
    float* st = raw + 11 * 128;         // 11 stages x {s[64], t[64]}

    size_t need = (size_t)(6 * NODE) * 4 + ((size_t)(N + 1) + N + E + 512) * 4 + (size_t)11 * 128 * 4 * 2;
    if (ws_size < need) return;  // fail loudly (output stays poisoned)

    float invN = 1.0f / (float)N;
    int nb = (N + 255) / 256;
    int gb = (N + 255) / 256;
    int eb = (E + 255) / 256;

    hipMemsetAsync(rc, 0, (size_t)(N + 1) * sizeof(int), stream);
    hipMemsetAsync(raw, 0, (size_t)11 * 128 * sizeof(float), stream);

    k_hist<<<eb, 256, 0, stream>>>(dstp, rc, E);
    k_scan1<<<nb, 256, 0, stream>>>(rc, part, N);
    k_scan2<<<1, 512, 0, stream>>>(part, nb, rc, N);
    k_scan3<<<nb, 256, 0, stream>>>(rc, part, rc, cursor, N);
    k_scatter<<<eb, 256, 0, stream>>>(srcp, dstp, cursor, col, E);

    // input projection
    k_gemm64<HID, false><<<gb, 256, 0, stream>>>(x, nullptr, W_in, b_in, pre0, N);
    k_colstats<<<512, 256, 0, stream>>>(pre0, raw, (long long)NODE);
    k_fin<<<1, 64, 0, stream>>>(raw, g_in, be_in, st, invN);

    float* zb[3] = {z0, z1, z2};
    for (int i = 0; i < LAYERS; i++) {
        int s1 = 1 + 3 * i, s2 = 2 + 3 * i, sp = 3 + 3 * i;
        const float* hb = (i == 0) ? pre0 : zb[i - 1];
        const float* sth = (i == 0) ? st : st + (size_t)(3 * i) * 128;  // stage0 or post-BN of prev layer
        k_agg<<<(N + 3) / 4, 256, 0, stream>>>(hb, sth, rc, col, epsp, i, o, N);
        k_gemm64<HID, false><<<gb, 256, 0, stream>>>(o, nullptr, W1 + (size_t)i * HID * HID, b1 + i * HID, p, N);
        k_colstats<<<512, 256, 0, stream>>>(p, raw + (size_t)s1 * 128, (long long)NODE);
        k_fin<<<1, 64, 0, stream>>>(raw + (size_t)s1 * 128, g1 + i * HID, be1 + i * HID, st + (size_t)s1 * 128, invN);
        k_gemm64<HID, true><<<gb, 256, 0, stream>>>(p, st + (size_t)s1 * 128, W2 + (size_t)i * HID * HID,
                                                    b2 + i * HID, zb[i], N);
        k_colstats<<<512, 256, 0, stream>>>(zb[i], raw + (size_t)s2 * 128, (long long)NODE);
        k_fin<<<1, 64, 0, stream>>>(raw + (size_t)s2 * 128, g2 + i * HID, be2 + i * HID, st + (size_t)s2 * 128, invN);
        k_affine_stats<<<512, 256, 0, stream>>>(zb[i], st + (size_t)s2 * 128, raw + (size_t)sp * 128, (long long)NODE);
        k_fin<<<1, 64, 0, stream>>>(raw + (size_t)sp * 128, g_post + i * HID, be_post + i * HID,
                                    st + (size_t)sp * 128, invN);
    }

    // head: concat -> 256x64 GEMM -> BN -> relu -> 64x10 GEMM
    k_gemm_out1<<<gb, 256, 0, stream>>>(pre0, z0, z1, z2,
                                        st, st + 3 * 128, st + 6 * 128, st + 9 * 128,
                                        W_out1, b_out1, p, N);
    k_colstats<<<512, 256, 0, stream>>>(p, raw + 10 * 128, (long long)NODE);
    k_fin<<<1, 64, 0, stream>>>(raw + 10 * 128, g_out, be_out, st + 10 * 128, invN);
    k_gemm64<10, true><<<gb, 256, 0, stream>>>(p, st + 10 * 128, W_out2, b_out2, (float*)d_out, N);
}

// Round 2
// 1164.851 us; speedup vs baseline: 1.2326x; 1.2326x over previous
//
#include <hip/hip_runtime.h>

// GIN forward, MI355X. Round 2:
//  - k_agg: hierarchical unroll (8/4/2/1) for gather MLP (was latency-serialized at 365 ns/iter)
//  - BN finalize (k_fin) folded into consumers: per-lane for agg/affine_stats, LDS-prologue for GEMMs
//  - CSR build (hist/scan/scatter) -> pull aggregation, no fp32 atomics

#define HID 64
#define LAYERS 3
#define BN_EPS 1e-5f

__device__ __forceinline__ float relu_aff(float x, float s, float t) {
    return fmaxf(fmaf(x, s, t), 0.f);
}

// compute affine (s,t) for column c from raw sums
__device__ __forceinline__ void bn_fin(const float* __restrict__ raw, const float* __restrict__ g,
                                       const float* __restrict__ b, float invN, int c,
                                       float& s, float& t) {
    float m = raw[c] * invN;
    float v = fmaf(-m, m, raw[64 + c] * invN);
    float r = rsqrtf(v + BN_EPS);
    s = r * g[c];
    t = fmaf(-m, s, b[c]);
}

// ---------------- CSR build ----------------
__global__ void k_hist(const int* __restrict__ dst, int* __restrict__ cnt, int E) {
    int e = blockIdx.x * 256 + threadIdx.x;
    if (e < E) atomicAdd(&cnt[dst[e]], 1);
}

__global__ void k_scan1(const int* __restrict__ cnt, int* __restrict__ part, int n) {
    __shared__ int sm[256];
    int i = blockIdx.x * 256 + threadIdx.x;
    sm[threadIdx.x] = (i < n) ? cnt[i] : 0;
    __syncthreads();
    for (int s = 128; s > 0; s >>= 1) {
        if (threadIdx.x < s) sm[threadIdx.x] += sm[threadIdx.x + s];
        __syncthreads();
    }
    if (threadIdx.x == 0) part[blockIdx.x] = sm[0];
}

__global__ void k_scan2(int* part, int nb, int* row_off, int N) {
    int lane = threadIdx.x & 63, wid = threadIdx.x >> 6;
    int v = (threadIdx.x < nb) ? part[threadIdx.x] : 0;
    int incl = v;
    for (int d = 1; d < 64; d <<= 1) { int y = __shfl_up(incl, d); if (lane >= d) incl += y; }
    __shared__ int ws[8];
    if (lane == 63) ws[wid] = incl;
    __syncthreads();
    if (threadIdx.x == 0) { int a = 0; for (int w = 0; w < 8; w++) { int t = ws[w]; ws[w] = a; a += t; } }
    __syncthreads();
    int excl = incl - v + ws[wid];
    if (threadIdx.x < nb) part[threadIdx.x] = excl;
    if (threadIdx.x == nb - 1) row_off[N] = excl + v;
}

__global__ void k_scan3(const int* cnt, const int* __restrict__ part,
                        int* row_off, int* cursor, int n) {
    int i = blockIdx.x * 256 + threadIdx.x;
    int lane = threadIdx.x & 63, wid = threadIdx.x >> 6;
    int v = (i < n) ? cnt[i] : 0;
    int incl = v;
    for (int d = 1; d < 64; d <<= 1) { int y = __shfl_up(incl, d); if (lane >= d) incl += y; }
    __shared__ int ws[4];
    if (lane == 63) ws[wid] = incl;
    __syncthreads();
    if (threadIdx.x == 0) { int a = 0; for (int w = 0; w < 4; w++) { int t = ws[w]; ws[w] = a; a += t; } }
    __syncthreads();
    int excl = incl - v + ws[wid] + part[blockIdx.x];
    if (i < n) { row_off[i] = excl; cursor[i] = excl; }
}

__global__ void k_scatter(const int* __restrict__ src, const int* __restrict__ dst,
                          int* __restrict__ cursor, int* __restrict__ col, int E) {
    int e = blockIdx.x * 256 + threadIdx.x;
    if (e < E) {
        int d = dst[e];
        int p = atomicAdd(&cursor[d], 1);
        col[p] = src[e];
    }
}

// ---------------- aggregation: o = (1+eps)*act(h) + sum act(h[src]) ----------------
// act = relu_aff with affine computed per-lane from raw sums. 1 wave/node, lane=feature.
// Hierarchical 8/4/2/1 unroll: up to 8 independent row gathers in flight per wave.
__global__ __launch_bounds__(256) void k_agg(const float* __restrict__ hb,
                                             const float* __restrict__ raw, const float* __restrict__ g,
                                             const float* __restrict__ b, float invN,
                                             const int* __restrict__ row_off, const int* __restrict__ col,
                                             const float* __restrict__ epsp, int li,
                                             float* __restrict__ o, int n) {
    int wid = threadIdx.x >> 6, lane = threadIdx.x & 63;
    int node = blockIdx.x * 4 + wid;
    if (node >= n) return;
    float s, t;
    bn_fin(raw, g, b, invN, lane, s, t);
    float ope = 1.f + epsp[li];
    float acc = ope * relu_aff(hb[(size_t)node * HID + lane], s, t);
    int e = row_off[node], b1 = row_off[node + 1];

    while (e + 8 <= b1) {
        int i0 = col[e], i1 = col[e + 1], i2 = col[e + 2], i3 = col[e + 3];
        int i4 = col[e + 4], i5 = col[e + 5], i6 = col[e + 6], i7 = col[e + 7];
        float v0 = hb[(size_t)i0 * HID + lane], v1 = hb[(size_t)i1 * HID + lane];
        float v2 = hb[(size_t)i2 * HID + lane], v3 = hb[(size_t)i3 * HID + lane];
        float v4 = hb[(size_t)i4 * HID + lane], v5 = hb[(size_t)i5 * HID + lane];
        float v6 = hb[(size_t)i6 * HID + lane], v7 = hb[(size_t)i7 * HID + lane];
        acc += relu_aff(v0, s, t) + relu_aff(v1, s, t) + relu_aff(v2, s, t) + relu_aff(v3, s, t);
        acc += relu_aff(v4, s, t) + relu_aff(v5, s, t) + relu_aff(v6, s, t) + relu_aff(v7, s, t);
        e += 8;
    }
    if (e + 4 <= b1) {
        int i0 = col[e], i1 = col[e + 1], i2 = col[e + 2], i3 = col[e + 3];
        float v0 = hb[(size_t)i0 * HID + lane], v1 = hb[(size_t)i1 * HID + lane];
        float v2 = hb[(size_t)i2 * HID + lane], v3 = hb[(size_t)i3 * HID + lane];
        acc += relu_aff(v0, s, t) + relu_aff(v1, s, t) + relu_aff(v2, s, t) + relu_aff(v3, s, t);
        e += 4;
    }
    if (e + 2 <= b1) {
        int i0 = col[e], i1 = col[e + 1];
        float v0 = hb[(size_t)i0 * HID + lane], v1 = hb[(size_t)i1 * HID + lane];
        acc += relu_aff(v0, s, t) + relu_aff(v1, s, t);
        e += 2;
    }
    if (e < b1) acc += relu_aff(hb[(size_t)col[e] * HID + lane], s, t);

    o[(size_t)node * HID + lane] = acc;
}

// ---------------- GEMM: C[n x NCOL] = act(A[n x 64]) @ W[64 x NCOL] + bias ----------------
// AFF: act = relu_aff with (s,t) computed into LDS at block start (from raw,g,b).
template <int NCOL, bool AFF>
__global__ __launch_bounds__(256) void k_gemm64(const float* __restrict__ A,
                                                const float* __restrict__ raw, const float* __restrict__ g,
                                                const float* __restrict__ b, float invN,
                                                const float* __restrict__ W, const float* __restrict__ bias,
                                                float* __restrict__ C, int n) {
    __shared__ float stl[2 * HID];
    if (AFF) {
        if (threadIdx.x < HID) {
            float s, t;
            bn_fin(raw, g, b, invN, threadIdx.x, s, t);
            stl[threadIdx.x] = s;
            stl[HID + threadIdx.x] = t;
        }
        __syncthreads();
    }
    int row = blockIdx.x * 256 + threadIdx.x;
    if (row >= n) return;
    float acc[NCOL];
#pragma unroll
    for (int j = 0; j < NCOL; j++) acc[j] = bias[j];
    const float4* a4 = (const float4*)(A + (size_t)row * HID);
    for (int kk = 0; kk < HID / 4; kk++) {
        float4 av = a4[kk];
        float a[4] = {av.x, av.y, av.z, av.w};
#pragma unroll
        for (int u = 0; u < 4; u++) {
            int k = kk * 4 + u;
            float xv = a[u];
            if (AFF) xv = relu_aff(xv, stl[k], stl[HID + k]);
#pragma unroll
            for (int j = 0; j < NCOL; j++) acc[j] = fmaf(xv, W[k * NCOL + j], acc[j]);
        }
    }
    float* c = C + (size_t)row * NCOL;
    if constexpr (NCOL % 4 == 0) {
#pragma unroll
        for (int j = 0; j < NCOL / 4; j++)
            ((float4*)c)[j] = make_float4(acc[4 * j], acc[4 * j + 1], acc[4 * j + 2], acc[4 * j + 3]);
    } else {
#pragma unroll
        for (int j = 0; j < NCOL; j++) c[j] = acc[j];
    }
}

// concat GEMM: C = [h0|h1|h2|h3] @ W[256 x 64] + bias, h_p = relu_aff(buf_p, s_p, t_p)
__global__ __launch_bounds__(256) void k_gemm_out1(const float* __restrict__ B0, const float* __restrict__ B1,
                                                   const float* __restrict__ B2, const float* __restrict__ B3,
                                                   const float* __restrict__ R0, const float* __restrict__ R1,
                                                   const float* __restrict__ R2, const float* __restrict__ R3,
                                                   const float* __restrict__ G0, const float* __restrict__ G1,
                                                   const float* __restrict__ G2, const float* __restrict__ G3,
                                                   const float* __restrict__ E0, const float* __restrict__ E1,
                                                   const float* __restrict__ E2, const float* __restrict__ E3,
                                                   float invN,
                                                   const float* __restrict__ W, const float* __restrict__ bias,
                                                   float* __restrict__ C, int n) {
    __shared__ float stl[4][2 * HID];
    {
        int p = threadIdx.x >> 6, c = threadIdx.x & 63;
        const float* rp[4] = {R0, R1, R2, R3};
        const float* gp[4] = {G0, G1, G2, G3};
        const float* ep[4] = {E0, E1, E2, E3};
        float s, t;
        bn_fin(rp[p], gp[p], ep[p], invN, c, s, t);
        stl[p][c] = s;
        stl[p][HID + c] = t;
        __syncthreads();
    }
    int row = blockIdx.x * 256 + threadIdx.x;
    if (row >= n) return;
    float acc[HID];
#pragma unroll
    for (int j = 0; j < HID; j++) acc[j] = bias[j];
    const float* bufs[4] = {B0, B1, B2, B3};
#pragma unroll
    for (int pp = 0; pp < 4; pp++) {
        const float4* a4 = (const float4*)(bufs[pp] + (size_t)row * HID);
        const float* Wp = W + pp * HID * HID;
        for (int kk = 0; kk < HID / 4; kk++) {
            float4 av = a4[kk];
            float a[4] = {av.x, av.y, av.z, av.w};
#pragma unroll
            for (int u = 0; u < 4; u++) {
                int k = kk * 4 + u;
                float xv = relu_aff(a[u], stl[pp][k], stl[pp][HID + k]);
#pragma unroll
                for (int j = 0; j < HID; j++) acc[j] = fmaf(xv, Wp[k * HID + j], acc[j]);
            }
        }
    }
    float4* c4 = (float4*)(C + (size_t)row * HID);
#pragma unroll
    for (int j = 0; j < HID / 4; j++)
        c4[j] = make_float4(acc[4 * j], acc[4 * j + 1], acc[4 * j + 2], acc[4 * j + 3]);
}

// ---------------- column stats (sum, sumsq) ----------------
__global__ __launch_bounds__(256) void k_colstats(const float* __restrict__ X, float* __restrict__ raw,
                                                  long long n64) {
    long long stride = (long long)gridDim.x * 256;
    long long i0 = (long long)blockIdx.x * 256 + threadIdx.x;
    int col = threadIdx.x & 63;
    float s = 0.f, q = 0.f;
    for (long long i = i0; i < n64; i += stride) { float v = X[i]; s += v; q = fmaf(v, v, q); }
    __shared__ float ls[256], lq[256];
    ls[threadIdx.x] = s; lq[threadIdx.x] = q;
    __syncthreads();
    if (threadIdx.x < 64) {
        s = ls[threadIdx.x] + ls[threadIdx.x + 64] + ls[threadIdx.x + 128] + ls[threadIdx.x + 192];
        q = lq[threadIdx.x] + lq[threadIdx.x + 64] + lq[threadIdx.x + 128] + lq[threadIdx.x + 192];
        atomicAdd(&raw[col], s);
        atomicAdd(&raw[64 + col], q);
    }
}

// in-place z = relu_aff(x, s2, t2) (affine from rawIn) + accumulate stats of z into rawOut
__global__ __launch_bounds__(256) void k_affine_stats(float* __restrict__ X,
                                                      const float* __restrict__ rawIn,
                                                      const float* __restrict__ g, const float* __restrict__ b,
                                                      float invN,
                                                      float* __restrict__ rawOut, long long n64) {
    long long stride = (long long)gridDim.x * 256;
    long long i0 = (long long)blockIdx.x * 256 + threadIdx.x;
    int col = threadIdx.x & 63;
    float sA, tA;
    bn_fin(rawIn, g, b, invN, col, sA, tA);
    float s = 0.f, q = 0.f;
    for (long long i = i0; i < n64; i += stride) {
        float v = relu_aff(X[i], sA, tA);
        X[i] = v;
        s += v; q = fmaf(v, v, q);
    }
    __shared__ float ls[256], lq[256];
    ls[threadIdx.x] = s; lq[threadIdx.x] = q;
    __syncthreads();
    if (threadIdx.x < 64) {
        s = ls[threadIdx.x] + ls[threadIdx.x + 64] + ls[threadIdx.x + 128] + ls[threadIdx.x + 192];
        q = lq[threadIdx.x] + lq[threadIdx.x + 64] + lq[threadIdx.x + 128] + lq[threadIdx.x + 192];
        atomicAdd(&rawOut[col], s);
        atomicAdd(&rawOut[64 + col], q);
    }
}

extern "C" void kernel_launch(void* const* d_in, const int* in_sizes, int n_in,
                              void* d_out, int out_size, void* d_ws, size_t ws_size,
                              hipStream_t stream) {
    const float* x = (const float*)d_in[0];
    const int* ei = (const int*)d_in[1];
    const float* W_in = (const float*)d_in[2];
    const float* b_in = (const float*)d_in[3];
    const float* g_in = (const float*)d_in[4];
    const float* be_in = (const float*)d_in[5];
    const float* epsp = (const float*)d_in[6];
    const float* W1 = (const float*)d_in[7];
    const float* b1 = (const float*)d_in[8];
    const float* g1 = (const float*)d_in[9];
    const float* be1 = (const float*)d_in[10];
    const float* W2 = (const float*)d_in[11];
    const float* b2 = (const float*)d_in[12];
    const float* g2 = (const float*)d_in[13];
    const float* be2 = (const float*)d_in[14];
    const float* g_post = (const float*)d_in[15];
    const float* be_post = (const float*)d_in[16];
    const float* W_out1 = (const float*)d_in[17];
    const float* b_out1 = (const float*)d_in[18];
    const float* g_out = (const float*)d_in[19];
    const float* be_out = (const float*)d_in[20];
    const float* W_out2 = (const float*)d_in[21];
    const float* b_out2 = (const float*)d_in[22];

    const int N = in_sizes[0] / HID;
    const int E = in_sizes[1] / 2;
    const int* srcp = ei;
    const int* dstp = ei + E;

    size_t NODE = (size_t)N * HID;
    float* f = (float*)d_ws;
    float* pre0 = f;                 // stage-0 pre-BN (kept for concat)
    float* z0 = f + NODE;            // layer pre2 -> (in place) post-BN2-relu, kept for concat
    float* z1 = f + 2 * NODE;
    float* z2 = f + 3 * NODE;
    float* o = f + 4 * NODE;         // aggregation output
    float* p = f + 5 * NODE;         // gemm1 output / head pre-BN (reused)
    int* rc = (int*)(f + 6 * NODE);  // counts -> row offsets, N+1
    int* cursor = rc + (N + 1);
    int* col = cursor + N;           // E
    int* part = col + E;             // scan partials, <=512
    float* raw = (float*)(part + 512);  // 11 stages x {sum[64], sumsq[64]}

    size_t need = (size_t)(6 * NODE) * 4 + ((size_t)(N + 1) + N + E + 512) * 4 + (size_t)11 * 128 * 4;
    if (ws_size < need) return;  // fail loudly (output stays poisoned)

    float invN = 1.0f / (float)N;
    int nb = (N + 255) / 256;
    int gb = (N + 255) / 256;
    int eb = (E + 255) / 256;

    hipMemsetAsync(rc, 0, (size_t)(N + 1) * sizeof(int), stream);
    hipMemsetAsync(raw, 0, (size_t)11 * 128 * sizeof(float), stream);

    k_hist<<<eb, 256, 0, stream>>>(dstp, rc, E);
    k_scan1<<<nb, 256, 0, stream>>>(rc, part, N);
    k_scan2<<<1, 512, 0, stream>>>(part, nb, rc, N);
    k_scan3<<<nb, 256, 0, stream>>>(rc, part, rc, cursor, N);
    k_scatter<<<eb, 256, 0, stream>>>(srcp, dstp, cursor, col, E);

    // input projection (no input affine)
    k_gemm64<HID, false><<<gb, 256, 0, stream>>>(x, nullptr, nullptr, nullptr, invN, W_in, b_in, pre0, N);
    k_colstats<<<512, 256, 0, stream>>>(pre0, raw, (long long)NODE);

    float* zb[3] = {z0, z1, z2};
    for (int i = 0; i < LAYERS; i++) {
        int s1 = 1 + 3 * i, s2 = 2 + 3 * i, sp = 3 + 3 * i;
        const float* hb = (i == 0) ? pre0 : zb[i - 1];
        // affine for act(hb): stage0 for i==0, else post-stage of layer i-1 (= 3*i)
        const float* rh = (i == 0) ? raw : raw + (size_t)(3 * i) * 128;
        const float* gh = (i == 0) ? g_in : g_post + (i - 1) * HID;
        const float* eh = (i == 0) ? be_in : be_post + (i - 1) * HID;
        k_agg<<<(N + 3) / 4, 256, 0, stream>>>(hb, rh, gh, eh, invN, rc, col, epsp, i, o, N);
        k_gemm64<HID, false><<<gb, 256, 0, stream>>>(o, nullptr, nullptr, nullptr, invN,
                                                     W1 + (size_t)i * HID * HID, b1 + i * HID, p, N);
        k_colstats<<<512, 256, 0, stream>>>(p, raw + (size_t)s1 * 128, (long long)NODE);
        k_gemm64<HID, true><<<gb, 256, 0, stream>>>(p, raw + (size_t)s1 * 128, g1 + i * HID, be1 + i * HID, invN,
                                                    W2 + (size_t)i * HID * HID, b2 + i * HID, zb[i], N);
        k_colstats<<<512, 256, 0, stream>>>(zb[i], raw + (size_t)s2 * 128, (long long)NODE);
        k_affine_stats<<<512, 256, 0, stream>>>(zb[i], raw + (size_t)s2 * 128, g2 + i * HID, be2 + i * HID, invN,
                                                raw + (size_t)sp * 128, (long long)NODE);
    }

    // head: concat -> 256x64 GEMM -> BN -> relu -> 64x10 GEMM
    k_gemm_out1<<<gb, 256, 0, stream>>>(pre0, z0, z1, z2,
                                        raw, raw + 3 * 128, raw + 6 * 128, raw + 9 * 128,
                                        g_in, g_post, g_post + HID, g_post + 2 * HID,
                                        be_in, be_post, be_post + HID, be_post + 2 * HID,
                                        invN, W_out1, b_out1, p, N);
    k_colstats<<<512, 256, 0, stream>>>(p, raw + 10 * 128, (long long)NODE);
    k_gemm64<10, true><<<gb, 256, 0, stream>>>(p, raw + 10 * 128, g_out, be_out, invN,
                                               W_out2, b_out2, (float*)d_out, N);
}